// Round 1
// baseline (187.914 us; speedup 1.0000x reference)
//
#include <hip/hip_runtime.h>
#include <math.h>

// ---- problem constants ----
constexpr int cB   = 64;
constexpr int cC   = 20;
constexpr int cNA  = 5;
constexpr int cH   = 19;
constexpr int cW   = 19;
constexpr int cT   = 50;
constexpr int cNB  = cB * cC;          // 1280
constexpr int cHW  = cH * cW;          // 361
constexpr int cA4  = cNA * cHW;        // 1805
constexpr int cCH  = cNA * 6;          // 30 channels
constexpr long cNTOT = (long)cNB * cA4; // 2,310,400
constexpr int cCLS_ROWS = cB * cA4;    // 115,520

// ---- workspace layout (bytes) ----
constexpr int ACC_BANKS = 64;
constexpr int TGT_N   = cNB * cT;              // 64000
constexpr size_t OFF_GX  = 4096;               // after accumulators (5x64 doubles used)
constexpr size_t OFF_GY  = OFF_GX  + (size_t)TGT_N * 4;
constexpr size_t OFF_GW  = OFF_GY  + (size_t)TGT_N * 4;
constexpr size_t OFF_GH  = OFF_GW  + (size_t)TGT_N * 4;
constexpr size_t OFF_CLS = OFF_GH  + (size_t)TGT_N * 4;
constexpr size_t OFF_VAL = OFF_CLS + (size_t)TGT_N * 4;
constexpr size_t OFF_WIN = OFF_VAL + (size_t)TGT_N * 4;

// =====================================================================
// Kernel A: per-target prep + winner (last-writer-wins) scatter.
// One thread per nb row, sequential over t (preserves scan order).
// =====================================================================
__global__ void k_prep(const float* __restrict__ target, const float* __restrict__ anch,
                       float* __restrict__ gx_, float* __restrict__ gy_,
                       float* __restrict__ gw_, float* __restrict__ gh_,
                       float* __restrict__ cls_, int* __restrict__ val_,
                       int* __restrict__ winner) {
    int nb = blockIdx.x * blockDim.x + threadIdx.x;
    if (nb >= cNB) return;
    const float* tg = target + (size_t)nb * (cT * 5);
    float aw[cNA], ah[cNA];
    for (int n = 0; n < cNA; ++n) { aw[n] = anch[2*n]; ah[n] = anch[2*n+1]; }
    int vrun = 1;
    for (int t = 0; t < cT; ++t) {
        float cv = tg[t*5 + 0];
        float xr = tg[t*5 + 1], yr = tg[t*5 + 2];
        float wr = tg[t*5 + 3], hr = tg[t*5 + 4];
        if (xr == 0.0f) vrun = 0;                 // cumprod(x != 0)
        float gx = xr * (float)cW, gy = yr * (float)cH;
        float gw = wr * (float)cW, gh = hr * (float)cH;
        int o = nb * cT + t;
        gx_[o] = gx; gy_[o] = gy; gw_[o] = gw; gh_[o] = gh;
        cls_[o] = cv; val_[o] = vrun;
        // best anchor: argmax of origin-aligned IoU, first-tie wins
        float best = -1.0f; int bn = 0;
        for (int n = 0; n < cNA; ++n) {
            float inter = fminf(gw, aw[n]) * fminf(gh, ah[n]);
            float uni   = gw*gh + aw[n]*ah[n] - inter;
            float r = inter / fmaxf(uni, 1e-12f);
            if (r > best) { best = r; bn = n; }
        }
        if (vrun) {
            int gi = (int)gx, gj = (int)gy;
            winner[(size_t)nb * cA4 + bn * cHW + gj * cW + gi] = t;
        }
    }
}

// =====================================================================
// Kernel B: per-cell losses (bce x/y, sq w/h, sq conf) + noobj mask.
// 4 cells per thread; targets broadcast from LDS as float4 corner boxes.
// =====================================================================
__launch_bounds__(256)
__global__ void k_main(const float* __restrict__ outp, const float* __restrict__ anch,
                       const float* __restrict__ gx_, const float* __restrict__ gy_,
                       const float* __restrict__ gw_, const float* __restrict__ gh_,
                       const int* __restrict__ val_, const int* __restrict__ winner,
                       double* __restrict__ acc) {
    __shared__ float4 s_box[cT];         // (l, r, top, bot)
    __shared__ float  s_ga06[cT];        // 0.6 * gt area (0 if invalid)
    __shared__ float  s_gx[cT], s_gy[cT], s_gw[cT], s_gh[cT];
    __shared__ float  s_aw[cNA], s_ah[cNA];
    __shared__ double s_red[3][4];
    const int tid  = threadIdx.x;
    const int nb   = blockIdx.x >> 1;
    const int base = ((blockIdx.x & 1) << 10) + tid;   // 0..1023 or 1024..2047

    if (tid < cT) {
        int o = nb * cT + tid;
        float gx = gx_[o], gy = gy_[o], gw = gw_[o], gh = gh_[o];
        s_gx[tid] = gx; s_gy[tid] = gy; s_gw[tid] = gw; s_gh[tid] = gh;
        if (val_[o]) {
            s_box[tid]  = make_float4(gx - 0.5f*gw, gx + 0.5f*gw, gy - 0.5f*gh, gy + 0.5f*gh);
            s_ga06[tid] = 0.6f * (gw * gh);
        } else {                                   // degenerate: inter == 0 always
            s_box[tid]  = make_float4(1e30f, -1e30f, 1e30f, -1e30f);
            s_ga06[tid] = 0.0f;
        }
    }
    if (tid < cNA) { s_aw[tid] = anch[2*tid]; s_ah[tid] = anch[2*tid+1]; }
    __syncthreads();

    float pl[4], pr[4], pt[4], pb[4], pa06[4];
    float conf[4], tconf[4];
    bool  wflag[4], active[4], over[4];
    float bce = 0.0f, sq = 0.0f;

    #pragma unroll
    for (int u = 0; u < 4; ++u) {
        int cell = base + (u << 8);
        bool act = cell < cA4;
        active[u] = act; over[u] = false; wflag[u] = false;
        conf[u] = 0.0f; tconf[u] = 0.0f;
        if (act) {
            int na  = cell / cHW;
            int rem = cell - na * cHW;
            int j   = rem / cW;
            int i   = rem - j * cW;
            const float* ob = outp + (size_t)nb * (cCH * cHW) + (size_t)(na * 6) * cHW + rem;
            float xl = ob[0], yl = ob[cHW], wl = ob[2*cHW], hl = ob[3*cHW], cl = ob[4*cHW];
            float x  = 1.0f / (1.0f + expf(-xl));
            float y  = 1.0f / (1.0f + expf(-yl));
            float cf = 1.0f / (1.0f + expf(-cl));
            float px = x + (float)i, py = y + (float)j;
            float pw = expf(wl) * s_aw[na], ph = expf(hl) * s_ah[na];
            float l0 = px - 0.5f*pw, r0 = px + 0.5f*pw;
            float t0 = py - 0.5f*ph, b0 = py + 0.5f*ph;
            float pa = pw * ph;
            pl[u] = l0; pr[u] = r0; pt[u] = t0; pb[u] = b0;
            pa06[u] = 0.6f * pa;
            conf[u] = cf;
            float tx = 0.5f, ty = 0.5f, tw = 0.0f, th = 0.0f;
            int wt = winner[(size_t)nb * cA4 + cell];
            if (wt >= 0) {
                wflag[u] = true;
                float gx = s_gx[wt], gy = s_gy[wt], gw = s_gw[wt], gh = s_gh[wt];
                tx = gx - (float)i; ty = gy - (float)j;
                tw = logf(fmaxf(gw, 1e-12f) / s_aw[na]);
                th = logf(fmaxf(gh, 1e-12f) / s_ah[na]);
                float iw = fminf(r0, gx + 0.5f*gw) - fmaxf(l0, gx - 0.5f*gw);
                float ih = fminf(b0, gy + 0.5f*gh) - fmaxf(t0, gy - 0.5f*gh);
                iw = fmaxf(iw, 0.0f); ih = fmaxf(ih, 0.0f);
                float inter = iw * ih;
                float uni   = gw*gh + pa - inter;
                tconf[u] = inter / fmaxf(uni, 1e-12f);
            }
            float pc = fminf(fmaxf(x, 1e-7f), 1.0f - 1e-7f);
            bce += -(tx * logf(pc) + (1.0f - tx) * logf(1.0f - pc));
            pc = fminf(fmaxf(y, 1e-7f), 1.0f - 1e-7f);
            bce += -(ty * logf(pc) + (1.0f - ty) * logf(1.0f - pc));
            float dw = wl - tw, dh = hl - th;
            sq += dw*dw + dh*dh;
        } else {
            pl[u] = 1e30f; pr[u] = -1e30f; pt[u] = 1e30f; pb[u] = -1e30f; pa06[u] = 0.0f;
        }
    }

    // any-target IoU > THRESH?  (division-free: 1.6*inter > 0.6*(pa+ga))
    for (int t = 0; t < cT; ++t) {
        float4 bx = s_box[t];
        float  ga = s_ga06[t];
        #pragma unroll
        for (int u = 0; u < 4; ++u) {
            float iw = fminf(pr[u], bx.y) - fmaxf(pl[u], bx.x);
            float ih = fminf(pb[u], bx.w) - fmaxf(pt[u], bx.z);
            iw = fmaxf(iw, 0.0f); ih = fmaxf(ih, 0.0f);
            float inter = iw * ih;
            over[u] = over[u] | (1.6f * inter > pa06[u] + ga);
        }
    }

    float sc = 0.0f;
    #pragma unroll
    for (int u = 0; u < 4; ++u) {
        if (!active[u]) continue;
        float cm = wflag[u] ? 1.0f : (over[u] ? 0.0f : 1.0f);
        float d  = (conf[u] - tconf[u]) * cm;
        sc += d * d;
    }

    // block reduction -> banked double atomics
    double v0 = (double)bce, v1 = (double)sq, v2 = (double)sc;
    for (int off = 32; off > 0; off >>= 1) {
        v0 += __shfl_down(v0, off);
        v1 += __shfl_down(v1, off);
        v2 += __shfl_down(v2, off);
    }
    int lane = tid & 63, wid = tid >> 6;
    if (lane == 0) { s_red[0][wid] = v0; s_red[1][wid] = v1; s_red[2][wid] = v2; }
    __syncthreads();
    if (tid == 0) {
        double a0 = s_red[0][0] + s_red[0][1] + s_red[0][2] + s_red[0][3];
        double a1 = s_red[1][0] + s_red[1][1] + s_red[1][2] + s_red[1][3];
        double a2 = s_red[2][0] + s_red[2][1] + s_red[2][2] + s_red[2][3];
        int bank = blockIdx.x & (ACC_BANKS - 1);
        atomicAdd(&acc[0*ACC_BANKS + bank], a0);
        atomicAdd(&acc[1*ACC_BANKS + bank], a1);
        atomicAdd(&acc[2*ACC_BANKS + bank], a2);
    }
}

// =====================================================================
// Kernel C: class NLL over rows (b, a) with exactly-one-class selection.
// =====================================================================
__launch_bounds__(256)
__global__ void k_cls(const float* __restrict__ outp, const float* __restrict__ cls_,
                      const int* __restrict__ winner, double* __restrict__ acc) {
    __shared__ double s_red[2][4];
    int tid = threadIdx.x;
    int row = blockIdx.x * 256 + tid;
    double nll = 0.0, ns = 0.0;
    if (row < cCLS_ROWS) {
        int b = row / cA4;
        int a = row - b * cA4;
        int cnt = 0, selc = -1, selw = -1;
        for (int c = 0; c < cC; ++c) {
            int wv = winner[(size_t)(b * cC + c) * cA4 + a];
            if (wv >= 0) { cnt++; selc = c; selw = wv; }
        }
        if (cnt == 1) {
            int na  = a / cHW;
            int rem = a - na * cHW;
            const float* ob = outp + ((size_t)b * cC * cCH + na * 6 + 5) * cHW + rem;
            float l[cC]; float m = -1e30f;
            for (int c = 0; c < cC; ++c) { l[c] = ob[(size_t)c * cCH * cHW]; m = fmaxf(m, l[c]); }
            float s = 0.0f;
            for (int c = 0; c < cC; ++c) s += expf(l[c] - m);
            int label = (int)cls_[(b * cC + selc) * cT + selw];
            nll = (double)(m + logf(s) - l[label]);
            ns  = 1.0;
        }
    }
    for (int off = 32; off > 0; off >>= 1) {
        nll += __shfl_down(nll, off);
        ns  += __shfl_down(ns, off);
    }
    int lane = tid & 63, wid = tid >> 6;
    if (lane == 0) { s_red[0][wid] = nll; s_red[1][wid] = ns; }
    __syncthreads();
    if (tid == 0) {
        double a0 = s_red[0][0] + s_red[0][1] + s_red[0][2] + s_red[0][3];
        double a1 = s_red[1][0] + s_red[1][1] + s_red[1][2] + s_red[1][3];
        int bank = blockIdx.x & (ACC_BANKS - 1);
        atomicAdd(&acc[3*ACC_BANKS + bank], a0);
        atomicAdd(&acc[4*ACC_BANKS + bank], a1);
    }
}

// =====================================================================
// Kernel D: finalize scalar loss.
// =====================================================================
__global__ void k_final(const double* __restrict__ acc, float* __restrict__ o) {
    double a0 = 0, a1 = 0, a2 = 0, a3 = 0, a4 = 0;
    for (int k = 0; k < ACC_BANKS; ++k) {
        a0 += acc[0*ACC_BANKS + k];
        a1 += acc[1*ACC_BANKS + k];
        a2 += acc[2*ACC_BANKS + k];
        a3 += acc[3*ACC_BANKS + k];
        a4 += acc[4*ACC_BANKS + k];
    }
    double Ninv = 1.0 / (double)cNTOT;
    double loss = a0 * Ninv            // loss_x + loss_y (COORD_SCALE=1)
                + 0.5 * a1 * Ninv      // loss_w + loss_h
                + 0.5 * a2 * Ninv      // loss_conf
                + a3 / fmax(a4, 1.0);  // loss_cls (CLASS_SCALE=1)
    o[0] = (float)loss;
}

extern "C" void kernel_launch(void* const* d_in, const int* in_sizes, int n_in,
                              void* d_out, int out_size, void* d_ws, size_t ws_size,
                              hipStream_t stream) {
    const float* output = (const float*)d_in[0];
    const float* target = (const float*)d_in[1];
    const float* anch   = (const float*)d_in[2];
    char* ws = (char*)d_ws;
    double* acc  = (double*)ws;
    float* gx_   = (float*)(ws + OFF_GX);
    float* gy_   = (float*)(ws + OFF_GY);
    float* gw_   = (float*)(ws + OFF_GW);
    float* gh_   = (float*)(ws + OFF_GH);
    float* cls_  = (float*)(ws + OFF_CLS);
    int*   val_  = (int*)  (ws + OFF_VAL);
    int*   winner= (int*)  (ws + OFF_WIN);

    hipMemsetAsync(acc, 0, 4096, stream);                          // accumulators
    hipMemsetAsync(winner, 0xFF, (size_t)cNTOT * 4, stream);       // winner = -1

    k_prep<<<(cNB + 63) / 64, 64, 0, stream>>>(target, anch, gx_, gy_, gw_, gh_, cls_, val_, winner);
    k_main<<<cNB * 2, 256, 0, stream>>>(output, anch, gx_, gy_, gw_, gh_, val_, winner, acc);
    k_cls<<<(cCLS_ROWS + 255) / 256, 256, 0, stream>>>(output, cls_, winner, acc);
    k_final<<<1, 1, 0, stream>>>(acc, (float*)d_out);
}

// Round 2
// 145.466 us; speedup vs baseline: 1.2918x; 1.2918x over previous
//
#include <hip/hip_runtime.h>
#include <math.h>

// ---- problem constants ----
constexpr int cB   = 64;
constexpr int cC   = 20;
constexpr int cNA  = 5;
constexpr int cH   = 19;
constexpr int cW   = 19;
constexpr int cT   = 50;
constexpr int cNB  = cB * cC;          // 1280
constexpr int cHW  = cH * cW;          // 361
constexpr int cA4  = cNA * cHW;        // 1805
constexpr int cCH  = cNA * 6;          // 30 channels
constexpr long cNTOT = (long)cNB * cA4; // 2,310,400
constexpr int cCLS_ROWS = cB * cA4;    // 115,520

// ---- workspace layout (bytes) ----
constexpr int ACC_BANKS = 64;
constexpr int TGT_N   = cNB * cT;              // 64000
constexpr size_t OFF_GX  = 4096;               // after accumulators (5x64 doubles)
constexpr size_t OFF_GY  = OFF_GX  + (size_t)TGT_N * 4;
constexpr size_t OFF_GW  = OFF_GY  + (size_t)TGT_N * 4;
constexpr size_t OFF_GH  = OFF_GW  + (size_t)TGT_N * 4;
constexpr size_t OFF_CLS = OFF_GH  + (size_t)TGT_N * 4;
constexpr size_t OFF_VAL = OFF_CLS + (size_t)TGT_N * 4;
constexpr size_t OFF_WIN = OFF_VAL + (size_t)TGT_N * 4;

// ---- fast transcendentals (raw HW ops: v_exp_f32 / v_log_f32 / v_rcp_f32) ----
__device__ __forceinline__ float fexp(float x) {
    return __builtin_amdgcn_exp2f(x * 1.4426950408889634f);
}
__device__ __forceinline__ float flog(float x) {
    return __builtin_amdgcn_logf(x) * 0.6931471805599453f;
}
__device__ __forceinline__ float frcp(float x) { return __builtin_amdgcn_rcpf(x); }
__device__ __forceinline__ float fsigmoid(float x) { return frcp(1.0f + fexp(-x)); }

// =====================================================================
// Kernel A: per-target prep, fully parallel. One wave (64 thr) per nb.
// Last-writer-wins over t  ==  atomicMax(winner, t).
// Block 0 also zeroes the accumulators (harness re-poisons d_ws).
// =====================================================================
__global__ void k_prep(const float* __restrict__ target, const float* __restrict__ anch,
                       float* __restrict__ gx_, float* __restrict__ gy_,
                       float* __restrict__ gw_, float* __restrict__ gh_,
                       float* __restrict__ cls_, int* __restrict__ val_,
                       int* __restrict__ winner, double* __restrict__ acc) {
    const int nb = blockIdx.x;
    const int t  = threadIdx.x;
    if (nb == 0) {
        for (int k = t; k < 5 * ACC_BANKS; k += 64) acc[k] = 0.0;
    }
    float cv = 0.f, xr = 1.f, yr = 0.f, wr = 0.f, hr = 0.f;
    if (t < cT) {
        const float* tg = target + (size_t)nb * (cT * 5) + t * 5;
        cv = tg[0]; xr = tg[1]; yr = tg[2]; wr = tg[3]; hr = tg[4];
    }
    // validity = cumprod(x != 0) over t  ->  no zero among lanes 0..t
    unsigned long long nz = __ballot(xr != 0.0f);
    bool valid = false;
    if (t < cT) {
        unsigned long long below = (t == 63) ? ~0ull : ((2ull << t) - 1ull);
        valid = ((~nz) & below) == 0ull;
        float gx = xr * (float)cW, gy = yr * (float)cH;
        float gw = wr * (float)cW, gh = hr * (float)cH;
        int o = nb * cT + t;
        gx_[o] = gx; gy_[o] = gy; gw_[o] = gw; gh_[o] = gh;
        cls_[o] = cv; val_[o] = valid ? 1 : 0;
        // best anchor: argmax IoU at origin, first-tie wins
        float best = -1.0f; int bn = 0;
        for (int n = 0; n < cNA; ++n) {
            float aw = anch[2*n], ah = anch[2*n+1];
            float inter = fminf(gw, aw) * fminf(gh, ah);
            float uni   = gw*gh + aw*ah - inter;
            float r = inter / fmaxf(uni, 1e-12f);
            if (r > best) { best = r; bn = n; }
        }
        if (valid) {
            int gi = (int)gx, gj = (int)gy;
            atomicMax(&winner[(size_t)nb * cA4 + bn * cHW + gj * cW + gi], t);
        }
    }
}

// =====================================================================
// Kernel B: per-cell losses (bce x/y, sq w/h, sq conf) + noobj mask.
// 4 cells per thread; targets broadcast from LDS as float4 corner boxes.
// =====================================================================
__launch_bounds__(256)
__global__ void k_main(const float* __restrict__ outp, const float* __restrict__ anch,
                       const float* __restrict__ gx_, const float* __restrict__ gy_,
                       const float* __restrict__ gw_, const float* __restrict__ gh_,
                       const int* __restrict__ val_, const int* __restrict__ winner,
                       double* __restrict__ acc) {
    __shared__ float4 s_box[cT];         // (l, r, top, bot)
    __shared__ float  s_ga06[cT];        // 0.6 * gt area (0 if invalid)
    __shared__ float  s_gx[cT], s_gy[cT], s_gw[cT], s_gh[cT];
    __shared__ float  s_aw[cNA], s_ah[cNA];
    __shared__ double s_red[3][4];
    const int tid  = threadIdx.x;
    const int nb   = blockIdx.x >> 1;
    const int base = ((blockIdx.x & 1) << 10) + tid;   // 0..1023 or 1024..2047

    if (tid < cT) {
        int o = nb * cT + tid;
        float gx = gx_[o], gy = gy_[o], gw = gw_[o], gh = gh_[o];
        s_gx[tid] = gx; s_gy[tid] = gy; s_gw[tid] = gw; s_gh[tid] = gh;
        if (val_[o]) {
            s_box[tid]  = make_float4(gx - 0.5f*gw, gx + 0.5f*gw, gy - 0.5f*gh, gy + 0.5f*gh);
            s_ga06[tid] = 0.6f * (gw * gh);
        } else {                                   // degenerate: inter == 0 always
            s_box[tid]  = make_float4(1e30f, -1e30f, 1e30f, -1e30f);
            s_ga06[tid] = 0.0f;
        }
    }
    if (tid < cNA) { s_aw[tid] = anch[2*tid]; s_ah[tid] = anch[2*tid+1]; }
    __syncthreads();

    float pl[4], pr[4], pt[4], pb[4], pa06[4], ov[4];
    float conf[4], tconf[4];
    bool  wflag[4], active[4];
    float bce = 0.0f, sq = 0.0f;

    #pragma unroll
    for (int u = 0; u < 4; ++u) {
        int cell = base + (u << 8);
        bool act = cell < cA4;
        active[u] = act; wflag[u] = false;
        conf[u] = 0.0f; tconf[u] = 0.0f; ov[u] = -1e30f;
        if (act) {
            int na  = cell / cHW;
            int rem = cell - na * cHW;
            int j   = rem / cW;
            int i   = rem - j * cW;
            const float* ob = outp + (size_t)nb * (cCH * cHW) + (size_t)(na * 6) * cHW + rem;
            float xl = ob[0], yl = ob[cHW], wl = ob[2*cHW], hl = ob[3*cHW], cl = ob[4*cHW];
            float x  = fsigmoid(xl);
            float y  = fsigmoid(yl);
            float cf = fsigmoid(cl);
            float px = x + (float)i, py = y + (float)j;
            float pw = fexp(wl) * s_aw[na], ph = fexp(hl) * s_ah[na];
            float l0 = px - 0.5f*pw, r0 = px + 0.5f*pw;
            float t0 = py - 0.5f*ph, b0 = py + 0.5f*ph;
            float pa = pw * ph;
            pl[u] = l0; pr[u] = r0; pt[u] = t0; pb[u] = b0;
            pa06[u] = 0.6f * pa;
            conf[u] = cf;
            float tx = 0.5f, ty = 0.5f, tw = 0.0f, th = 0.0f;
            int wt = winner[(size_t)nb * cA4 + cell];
            if (wt >= 0) {
                wflag[u] = true;
                float gx = s_gx[wt], gy = s_gy[wt], gw = s_gw[wt], gh = s_gh[wt];
                tx = gx - (float)i; ty = gy - (float)j;
                tw = flog(fmaxf(gw, 1e-12f) * frcp(s_aw[na]));
                th = flog(fmaxf(gh, 1e-12f) * frcp(s_ah[na]));
                float iw = fminf(r0, gx + 0.5f*gw) - fmaxf(l0, gx - 0.5f*gw);
                float ih = fminf(b0, gy + 0.5f*gh) - fmaxf(t0, gy - 0.5f*gh);
                iw = fmaxf(iw, 0.0f); ih = fmaxf(ih, 0.0f);
                float inter = iw * ih;
                float uni   = gw*gh + pa - inter;
                tconf[u] = inter * frcp(fmaxf(uni, 1e-12f));
            }
            float pc = fminf(fmaxf(x, 1e-7f), 1.0f - 1e-7f);
            bce += -(tx * flog(pc) + (1.0f - tx) * flog(1.0f - pc));
            pc = fminf(fmaxf(y, 1e-7f), 1.0f - 1e-7f);
            bce += -(ty * flog(pc) + (1.0f - ty) * flog(1.0f - pc));
            float dw = wl - tw, dh = hl - th;
            sq += dw*dw + dh*dh;
        } else {
            pl[u] = 1e30f; pr[u] = -1e30f; pt[u] = 1e30f; pb[u] = -1e30f; pa06[u] = 0.0f;
        }
    }

    // any-target IoU > THRESH?  division-free:
    //   1.6*inter > 0.6*(pa+ga)  <=>  (1.6*inter - 0.6*ga) > 0.6*pa
    // accumulate lhs max over t, compare once vs 0.6*pa at the end (11 ops/pair)
    for (int t = 0; t < cT; ++t) {
        float4 bx = s_box[t];
        float  ga = s_ga06[t];
        #pragma unroll
        for (int u = 0; u < 4; ++u) {
            float iw = fminf(pr[u], bx.y) - fmaxf(pl[u], bx.x);
            float ih = fminf(pb[u], bx.w) - fmaxf(pt[u], bx.z);
            iw = fmaxf(iw, 0.0f); ih = fmaxf(ih, 0.0f);
            float inter = iw * ih;
            ov[u] = fmaxf(ov[u], __builtin_fmaf(1.6f, inter, -ga));
        }
    }

    float sc = 0.0f;
    #pragma unroll
    for (int u = 0; u < 4; ++u) {
        if (!active[u]) continue;
        bool over = ov[u] > pa06[u];
        float cm = wflag[u] ? 1.0f : (over ? 0.0f : 1.0f);
        float d  = (conf[u] - tconf[u]) * cm;
        sc += d * d;
    }

    // block reduction -> banked double atomics
    double v0 = (double)bce, v1 = (double)sq, v2 = (double)sc;
    for (int off = 32; off > 0; off >>= 1) {
        v0 += __shfl_down(v0, off);
        v1 += __shfl_down(v1, off);
        v2 += __shfl_down(v2, off);
    }
    int lane = tid & 63, wid = tid >> 6;
    if (lane == 0) { s_red[0][wid] = v0; s_red[1][wid] = v1; s_red[2][wid] = v2; }
    __syncthreads();
    if (tid == 0) {
        double a0 = s_red[0][0] + s_red[0][1] + s_red[0][2] + s_red[0][3];
        double a1 = s_red[1][0] + s_red[1][1] + s_red[1][2] + s_red[1][3];
        double a2 = s_red[2][0] + s_red[2][1] + s_red[2][2] + s_red[2][3];
        int bank = blockIdx.x & (ACC_BANKS - 1);
        atomicAdd(&acc[0*ACC_BANKS + bank], a0);
        atomicAdd(&acc[1*ACC_BANKS + bank], a1);
        atomicAdd(&acc[2*ACC_BANKS + bank], a2);
    }
}

// =====================================================================
// Kernel C: class NLL over rows (b, a) with exactly-one-class selection.
// =====================================================================
__launch_bounds__(256)
__global__ void k_cls(const float* __restrict__ outp, const float* __restrict__ cls_,
                      const int* __restrict__ winner, double* __restrict__ acc) {
    __shared__ double s_red[2][4];
    int tid = threadIdx.x;
    int row = blockIdx.x * 256 + tid;
    double nll = 0.0, ns = 0.0;
    if (row < cCLS_ROWS) {
        int b = row / cA4;
        int a = row - b * cA4;
        int cnt = 0, selc = -1, selw = -1;
        for (int c = 0; c < cC; ++c) {
            int wv = winner[(size_t)(b * cC + c) * cA4 + a];
            if (wv >= 0) { cnt++; selc = c; selw = wv; }
        }
        if (cnt == 1) {
            int na  = a / cHW;
            int rem = a - na * cHW;
            const float* ob = outp + ((size_t)b * cC * cCH + na * 6 + 5) * cHW + rem;
            float l[cC]; float m = -1e30f;
            for (int c = 0; c < cC; ++c) { l[c] = ob[(size_t)c * cCH * cHW]; m = fmaxf(m, l[c]); }
            float s = 0.0f;
            for (int c = 0; c < cC; ++c) s += fexp(l[c] - m);
            int label = (int)cls_[(b * cC + selc) * cT + selw];
            nll = (double)(m + flog(s) - l[label]);
            ns  = 1.0;
        }
    }
    for (int off = 32; off > 0; off >>= 1) {
        nll += __shfl_down(nll, off);
        ns  += __shfl_down(ns, off);
    }
    int lane = tid & 63, wid = tid >> 6;
    if (lane == 0) { s_red[0][wid] = nll; s_red[1][wid] = ns; }
    __syncthreads();
    if (tid == 0) {
        double a0 = s_red[0][0] + s_red[0][1] + s_red[0][2] + s_red[0][3];
        double a1 = s_red[1][0] + s_red[1][1] + s_red[1][2] + s_red[1][3];
        int bank = blockIdx.x & (ACC_BANKS - 1);
        atomicAdd(&acc[3*ACC_BANKS + bank], a0);
        atomicAdd(&acc[4*ACC_BANKS + bank], a1);
    }
}

// =====================================================================
// Kernel D: finalize scalar loss (one wave, shuffle-reduce the banks).
// =====================================================================
__global__ void k_final(const double* __restrict__ acc, float* __restrict__ o) {
    int lane = threadIdx.x;
    double s[5];
    #pragma unroll
    for (int j = 0; j < 5; ++j) {
        double v = acc[j * ACC_BANKS + lane];
        for (int off = 32; off > 0; off >>= 1) v += __shfl_down(v, off);
        s[j] = v;
    }
    if (lane == 0) {
        double Ninv = 1.0 / (double)cNTOT;
        double loss = s[0] * Ninv            // loss_x + loss_y (COORD_SCALE=1)
                    + 0.5 * s[1] * Ninv      // loss_w + loss_h
                    + 0.5 * s[2] * Ninv      // loss_conf
                    + s[3] / fmax(s[4], 1.0);// loss_cls (CLASS_SCALE=1)
        o[0] = (float)loss;
    }
}

extern "C" void kernel_launch(void* const* d_in, const int* in_sizes, int n_in,
                              void* d_out, int out_size, void* d_ws, size_t ws_size,
                              hipStream_t stream) {
    const float* output = (const float*)d_in[0];
    const float* target = (const float*)d_in[1];
    const float* anch   = (const float*)d_in[2];
    char* ws = (char*)d_ws;
    double* acc  = (double*)ws;
    float* gx_   = (float*)(ws + OFF_GX);
    float* gy_   = (float*)(ws + OFF_GY);
    float* gw_   = (float*)(ws + OFF_GW);
    float* gh_   = (float*)(ws + OFF_GH);
    float* cls_  = (float*)(ws + OFF_CLS);
    int*   val_  = (int*)  (ws + OFF_VAL);
    int*   winner= (int*)  (ws + OFF_WIN);

    hipMemsetAsync(winner, 0xFF, (size_t)cNTOT * 4, stream);       // winner = -1

    k_prep<<<cNB, 64, 0, stream>>>(target, anch, gx_, gy_, gw_, gh_, cls_, val_, winner, acc);
    k_main<<<cNB * 2, 256, 0, stream>>>(output, anch, gx_, gy_, gw_, gh_, val_, winner, acc);
    k_cls<<<(cCLS_ROWS + 255) / 256, 256, 0, stream>>>(output, cls_, winner, acc);
    k_final<<<1, 64, 0, stream>>>(acc, (float*)d_out);
}